// Round 1
// baseline (79.078 us; speedup 1.0000x reference)
//
#include <hip/hip_runtime.h>
#include <hip/hip_bf16.h>

// Problem constants (from reference setup_inputs): P=512, K=4, D=256, N=4096.
constexpr int D4 = 64;   // D/4 float4 per row, one per lane
constexpr int KP = 4;    // positives per row

// soft_rank (KL, strength=2) for a 4-vector of distances (d2 = squared dists).
__device__ __forceinline__ void soft_rank4(const float d2[4], float r[4]) {
    float th[4]; int p[4] = {0, 1, 2, 3};
#pragma unroll
    for (int t = 0; t < 4; ++t) th[t] = 0.5f * sqrtf(fmaxf(d2[t], 1e-12f));
    // stable bubble sort, descending (matches argsort(-theta) stable tie-break)
#define CSWAP(a, b)                                                           \
    if (th[a] < th[b]) {                                                      \
        float tt = th[a]; th[a] = th[b]; th[b] = tt;                          \
        int tp = p[a]; p[a] = p[b]; p[b] = tp;                                \
    }
    CSWAP(0, 1) CSWAP(1, 2) CSWAP(2, 3) CSWAP(0, 1) CSWAP(1, 2) CSWAP(0, 1)
#undef CSWAP
    // B[i][j] = LSE(th[i..j]) - log(sum w[i..j]), w = [4,3,2,1]
    const float logW[4][4] = {
        {1.3862944f, 1.9459101f, 2.1972246f, 2.3025851f},   // 4,7,9,10
        {0.f,        1.0986123f, 1.6094379f, 1.7917595f},   //   3,5,6
        {0.f,        0.f,        0.6931472f, 1.0986123f},   //     2,3
        {0.f,        0.f,        0.f,        0.f}};         //       1
    float B[4][4];
#pragma unroll
    for (int i = 0; i < 4; ++i) {
        float run = 0.f;
#pragma unroll
        for (int j = 0; j < 4; ++j) {
            if (j >= i) {
                run += __expf(th[j] - th[i]);  // th sorted desc -> arg <= 0
                B[i][j] = th[i] + __logf(run) - logW[i][j];
            }
        }
    }
    // dual[k] = min_{i<=k} max_{j>=k} B[i][j]; rank_sorted = exp(th - dual)
    float rs[4];
#pragma unroll
    for (int k = 0; k < 4; ++k) {
        float dual = 1e30f;
#pragma unroll
        for (int i = 0; i < 4; ++i) {
            if (i <= k) {
                float mx = -1e30f;
#pragma unroll
                for (int j = 0; j < 4; ++j)
                    if (j >= k) mx = fmaxf(mx, B[i][j]);
                dual = fminf(dual, mx);
            }
        }
        rs[k] = __expf(th[k] - dual);
    }
    // scatter back by inverse permutation (select chain, no dynamic indexing)
#pragma unroll
    for (int t = 0; t < 4; ++t) {
        float v = rs[3];
        v = (p[2] == t) ? rs[2] : v;
        v = (p[1] == t) ? rs[1] : v;
        v = (p[0] == t) ? rs[0] : v;
        r[t] = v;
    }
}

__device__ __forceinline__ float spearman4(const float a[4], const float b[4]) {
    float ma = 0.25f * (a[0] + a[1] + a[2] + a[3]);
    float mb = 0.25f * (b[0] + b[1] + b[2] + b[3]);
    float sab = 0.f, saa = 0.f, sbb = 0.f;
#pragma unroll
    for (int t = 0; t < 4; ++t) {
        float x = a[t] - ma, y = b[t] - mb;
        sab += x * y; saa += x * x; sbb += y * y;
    }
    return sab * rsqrtf(saa * sbb);
}

__global__ __launch_bounds__(256) void cmrr_main(
        const float* __restrict__ f0, const float* __restrict__ f1,
        const float* __restrict__ f2, const int* __restrict__ target,
        float* __restrict__ block_sums, int N) {
    const float* F[3] = {f0, f1, f2};
    const int wave = threadIdx.x >> 6;
    const int lane = threadIdx.x & 63;
    const int row = blockIdx.x * 4 + wave;
    float loss = 0.f;
    if (row < N) {
        const int id = target[row];
        const int base = (row < (N >> 1)) ? (N >> 1) : 0;
        const int j0 = base + KP * id;
        float d2[3][4];
#pragma unroll
        for (int f = 0; f < 3; ++f) {
            const float4* xi = (const float4*)(F[f] + (size_t)row * (D4 * 4));
            const float4 a = xi[lane];
#pragma unroll
            for (int t = 0; t < 4; ++t) {
                const float4* xj =
                    (const float4*)(F[f] + (size_t)(j0 + t) * (D4 * 4));
                const float4 b = xj[lane];
                const float dx = a.x - b.x, dy = a.y - b.y;
                const float dz = a.z - b.z, dw = a.w - b.w;
                d2[f][t] = dx * dx + dy * dy + dz * dz + dw * dw;
            }
        }
        // butterfly reduce each of the 12 partials across the 64-lane wave
#pragma unroll
        for (int f = 0; f < 3; ++f) {
#pragma unroll
            for (int t = 0; t < 4; ++t) {
                float v = d2[f][t];
#pragma unroll
                for (int m = 32; m >= 1; m >>= 1) v += __shfl_xor(v, m, 64);
                d2[f][t] = v;
            }
        }
        float ranks[3][4];
#pragma unroll
        for (int f = 0; f < 3; ++f) soft_rank4(d2[f], ranks[f]);
        const float c01 = spearman4(ranks[0], ranks[1]);
        const float c02 = spearman4(ranks[0], ranks[2]);
        const float c12 = spearman4(ranks[1], ranks[2]);
        loss = (c01 + c02 + c12 + 3.f) * (0.5f / 3.f);
    }
    __shared__ float ws4[4];
    if (lane == 0) ws4[wave] = loss;
    __syncthreads();
    if (threadIdx.x == 0)
        block_sums[blockIdx.x] = (ws4[0] + ws4[1]) + (ws4[2] + ws4[3]);
}

__global__ __launch_bounds__(256) void cmrr_reduce(
        const float* __restrict__ block_sums, float* __restrict__ out,
        int nblocks, float inv_n) {
    float s = 0.f;
    for (int i = threadIdx.x; i < nblocks; i += 256) s += block_sums[i];
#pragma unroll
    for (int m = 32; m >= 1; m >>= 1) s += __shfl_xor(s, m, 64);
    __shared__ float w[4];
    if ((threadIdx.x & 63) == 0) w[threadIdx.x >> 6] = s;
    __syncthreads();
    if (threadIdx.x == 0) out[0] = ((w[0] + w[1]) + (w[2] + w[3])) * inv_n;
}

extern "C" void kernel_launch(void* const* d_in, const int* in_sizes, int n_in,
                              void* d_out, int out_size, void* d_ws,
                              size_t ws_size, hipStream_t stream) {
    const float* f0 = (const float*)d_in[0];
    const float* f1 = (const float*)d_in[1];
    const float* f2 = (const float*)d_in[2];
    const int* target = (const int*)d_in[3];
    const int N = in_sizes[3];            // 4096
    const int nblocks = (N + 3) / 4;      // 4 waves (rows) per 256-thread block
    float* bs = (float*)d_ws;             // nblocks floats of scratch
    cmrr_main<<<nblocks, 256, 0, stream>>>(f0, f1, f2, target, bs, N);
    cmrr_reduce<<<1, 256, 0, stream>>>(bs, (float*)d_out, nblocks,
                                       1.0f / (float)N);
}